// Round 18
// baseline (312.248 us; speedup 1.0000x reference)
//
#include <hip/hip_runtime.h>

// Problem constants: B=16, NEG=128, S=128, D=512, N_PRED=12
#define DIM 512
#define M_ROWS 2048      // B*S

typedef __attribute__((ext_vector_type(8))) short short8;   // 8 bf16 (4 VGPRs)
typedef __attribute__((ext_vector_type(4))) float f32x4;

// f32 -> bf16 round-to-nearest-even (inputs are well-scaled, no NaN expected)
static __device__ __forceinline__ short f2bf(float x) {
    unsigned int u = __builtin_bit_cast(unsigned int, x);
    u += 0x7fffu + ((u >> 16) & 1u);
    return (short)(u >> 16);
}

// ---------------- Kernel 1: c_proj = c @ W[k]^T + b[k], bf16 MFMA ----------------
// (unchanged from R3 — ~5 us, verified)
#define K1_PAD 40
__global__ __launch_bounds__(256) void cproj_mfma(
    const float* __restrict__ c, const float* __restrict__ W,
    const float* __restrict__ bias, const int* __restrict__ kptr,
    float* __restrict__ cp) {
    const int ksel = kptr[0];
    const float* __restrict__ Wk = W + (size_t)ksel * DIM * DIM;
    const float* __restrict__ bk = bias + (size_t)ksel * DIM;

    __shared__ short Alds[64][K1_PAD];
    __shared__ short Blds[64][K1_PAD];

    const int bm = blockIdx.x & 31;
    const int bn = blockIdx.x >> 5;
    const int t  = threadIdx.x;
    const int lane = t & 63;
    const int wv   = t >> 6;

    const int srow = t >> 2;
    const int sk   = (t & 3) * 8;

    const float* Ap = c  + (size_t)(bm * 64 + srow) * DIM + sk;
    const float* Bp = Wk + (size_t)(bn * 64 + srow) * DIM + sk;

    float4 a0 = *(const float4*)Ap,       a1 = *(const float4*)(Ap + 4);
    float4 b0 = *(const float4*)Bp,       b1 = *(const float4*)(Bp + 4);

    f32x4 acc[4] = {};

    const int frow = lane & 15;
    const int fk   = (lane >> 4) * 8;

    for (int step = 0; step < 16; ++step) {
        __syncthreads();
        short8 av, bv;
        av[0] = f2bf(a0.x); av[1] = f2bf(a0.y); av[2] = f2bf(a0.z); av[3] = f2bf(a0.w);
        av[4] = f2bf(a1.x); av[5] = f2bf(a1.y); av[6] = f2bf(a1.z); av[7] = f2bf(a1.w);
        bv[0] = f2bf(b0.x); bv[1] = f2bf(b0.y); bv[2] = f2bf(b0.z); bv[3] = f2bf(b0.w);
        bv[4] = f2bf(b1.x); bv[5] = f2bf(b1.y); bv[6] = f2bf(b1.z); bv[7] = f2bf(b1.w);
        *(short8*)&Alds[srow][sk] = av;
        *(short8*)&Blds[srow][sk] = bv;
        __syncthreads();
        if (step < 15) {
            const int off = (step + 1) * 32;
            a0 = *(const float4*)(Ap + off); a1 = *(const float4*)(Ap + off + 4);
            b0 = *(const float4*)(Bp + off); b1 = *(const float4*)(Bp + off + 4);
        }
        const short8 bfrag = *(const short8*)&Blds[wv * 16 + frow][fk];
#pragma unroll
        for (int f = 0; f < 4; ++f) {
            const short8 afrag = *(const short8*)&Alds[f * 16 + frow][fk];
            acc[f] = __builtin_amdgcn_mfma_f32_16x16x32_bf16(afrag, bfrag, acc[f], 0, 0, 0);
        }
    }

    const int col = bn * 64 + wv * 16 + frow;
    const float bias_v = bk[col];
    const int r0 = (lane >> 4) * 4;
#pragma unroll
    for (int f = 0; f < 4; ++f)
#pragma unroll
        for (int r = 0; r < 4; ++r)
            cp[(size_t)(bm * 64 + f * 16 + r0 + r) * DIM + col] = acc[f][r] + bias_v;
}

// ---------------- Kernel 2: out[b,n,s] = (1/512) * dot(cp[b,s,:], z[b,n,s,:]) ----
// R13 best structure (nt one-shot 4-slot) + R6-proven reps diagnostic: cp
// loaded once, then the {8 nt z-loads + 4 dot/reduce/store} body repeats
// `reps` times with a runtime-zero pointer delta (defeats CSE). Each rep
// computes and stores IDENTICAL outputs -> deterministic/idempotent; no
// buffer outside out is written. Purpose: first counter capture of the nt
// variant (per-rep HBM cost visible since nt skips L3).
#define NS ((size_t)128 * 512)         // n-stride in z (floats)
#define LD4(p)   (*(const f32x4*)(p))
#define LD4NT(p) (__builtin_nontemporal_load((const f32x4*)(p)))

__global__ __launch_bounds__(256) void dot_kernel(
    const float* __restrict__ z, const float* __restrict__ cp,
    float* __restrict__ out, int reps, size_t rep_delta) {
    const int blk  = blockIdx.x;             // 0..16383
    const int bs   = blk >> 3;               // b*128 + s (0..2047)
    const int noct = blk & 7;                // n-group of 16
    const int wave = threadIdx.x >> 6;       // 0..3
    const int lane = threadIdx.x & 63;
    const int b = bs >> 7;
    const int s = bs & 127;

    // cp row -> registers (temporal; loaded once)
    const float* cpr = cp + (size_t)bs * DIM + lane * 4;
    const f32x4 c0 = LD4(cpr);
    const f32x4 c1 = LD4(cpr + 256);

    const int nbase = noct * 16 + wave * 4;
    const float* zp = z + (((size_t)(b * 128 + nbase)) * 128 + s) * DIM + lane * 4;
    float* outp = out + ((size_t)(b * 128 + nbase)) * 128 + s;

    for (int rep = 0; rep < reps; ++rep) {
        const f32x4 zA0 = LD4NT(zp + 0 * NS), zA1 = LD4NT(zp + 0 * NS + 256);
        const f32x4 zB0 = LD4NT(zp + 1 * NS), zB1 = LD4NT(zp + 1 * NS + 256);
        const f32x4 zC0 = LD4NT(zp + 2 * NS), zC1 = LD4NT(zp + 2 * NS + 256);
        const f32x4 zD0 = LD4NT(zp + 3 * NS), zD1 = LD4NT(zp + 3 * NS + 256);

#define SLOT(Z0, Z1, II)                                                      \
    {                                                                          \
        float acc = Z0[0] * c0[0];                                             \
        acc = fmaf(Z0[1], c0[1], acc);                                         \
        acc = fmaf(Z0[2], c0[2], acc);                                         \
        acc = fmaf(Z0[3], c0[3], acc);                                         \
        acc = fmaf(Z1[0], c1[0], acc);                                         \
        acc = fmaf(Z1[1], c1[1], acc);                                         \
        acc = fmaf(Z1[2], c1[2], acc);                                         \
        acc = fmaf(Z1[3], c1[3], acc);                                         \
        _Pragma("unroll")                                                      \
        for (int off = 32; off; off >>= 1) acc += __shfl_xor(acc, off);        \
        if (lane == 0) outp[(size_t)(II) * 128] = acc * (1.0f / 512.0f);       \
    }

        SLOT(zA0, zA1, 0)
        SLOT(zB0, zB1, 1)
        SLOT(zC0, zC1, 2)
        SLOT(zD0, zD1, 3)
#undef SLOT
        zp += rep_delta;   // runtime 0: defeats cross-rep CSE, keeps semantics
    }
}

extern "C" void kernel_launch(void* const* d_in, const int* in_sizes, int n_in,
                              void* d_out, int out_size, void* d_ws, size_t ws_size,
                              hipStream_t stream) {
    const float* c    = (const float*)d_in[0];
    const float* z    = (const float*)d_in[1];
    const float* W    = (const float*)d_in[2];
    const float* bias = (const float*)d_in[3];
    const int*   kptr = (const int*)d_in[4];
    float* out = (float*)d_out;
    float* cp  = (float*)d_ws;   // 2048*512*4 = 4 MB scratch for c_proj

    // Kernel 1: 32 M-tiles x 8 N-tiles = 256 blocks, bf16 MFMA
    cproj_mfma<<<dim3(256), dim3(256), 0, stream>>>(c, W, bias, kptr, cp);
    // Kernel 2: R13 best + reps=4 diagnostic (idempotent, R6-proven pattern)
    dot_kernel<<<dim3(16384), dim3(256), 0, stream>>>(z, cp, out, 4, (size_t)0);
}

// Round 19
// 101.973 us; speedup vs baseline: 3.0621x; 3.0621x over previous
//
#include <hip/hip_runtime.h>

// Problem constants: B=16, NEG=128, S=128, D=512, N_PRED=12
#define DIM 512
#define M_ROWS 2048      // B*S

typedef __attribute__((ext_vector_type(8))) short short8;   // 8 bf16 (4 VGPRs)
typedef __attribute__((ext_vector_type(4))) float f32x4;

// f32 -> bf16 round-to-nearest-even (inputs are well-scaled, no NaN expected)
static __device__ __forceinline__ short f2bf(float x) {
    unsigned int u = __builtin_bit_cast(unsigned int, x);
    u += 0x7fffu + ((u >> 16) & 1u);
    return (short)(u >> 16);
}

// ---------------- Kernel 1: c_proj = c @ W[k]^T + b[k], bf16 MFMA ----------------
// (unchanged from R3 — ~5 us, verified)
#define K1_PAD 40
__global__ __launch_bounds__(256) void cproj_mfma(
    const float* __restrict__ c, const float* __restrict__ W,
    const float* __restrict__ bias, const int* __restrict__ kptr,
    float* __restrict__ cp) {
    const int ksel = kptr[0];
    const float* __restrict__ Wk = W + (size_t)ksel * DIM * DIM;
    const float* __restrict__ bk = bias + (size_t)ksel * DIM;

    __shared__ short Alds[64][K1_PAD];
    __shared__ short Blds[64][K1_PAD];

    const int bm = blockIdx.x & 31;
    const int bn = blockIdx.x >> 5;
    const int t  = threadIdx.x;
    const int lane = t & 63;
    const int wv   = t >> 6;

    const int srow = t >> 2;
    const int sk   = (t & 3) * 8;

    const float* Ap = c  + (size_t)(bm * 64 + srow) * DIM + sk;
    const float* Bp = Wk + (size_t)(bn * 64 + srow) * DIM + sk;

    float4 a0 = *(const float4*)Ap,       a1 = *(const float4*)(Ap + 4);
    float4 b0 = *(const float4*)Bp,       b1 = *(const float4*)(Bp + 4);

    f32x4 acc[4] = {};

    const int frow = lane & 15;
    const int fk   = (lane >> 4) * 8;

    for (int step = 0; step < 16; ++step) {
        __syncthreads();
        short8 av, bv;
        av[0] = f2bf(a0.x); av[1] = f2bf(a0.y); av[2] = f2bf(a0.z); av[3] = f2bf(a0.w);
        av[4] = f2bf(a1.x); av[5] = f2bf(a1.y); av[6] = f2bf(a1.z); av[7] = f2bf(a1.w);
        bv[0] = f2bf(b0.x); bv[1] = f2bf(b0.y); bv[2] = f2bf(b0.z); bv[3] = f2bf(b0.w);
        bv[4] = f2bf(b1.x); bv[5] = f2bf(b1.y); bv[6] = f2bf(b1.z); bv[7] = f2bf(b1.w);
        *(short8*)&Alds[srow][sk] = av;
        *(short8*)&Blds[srow][sk] = bv;
        __syncthreads();
        if (step < 15) {
            const int off = (step + 1) * 32;
            a0 = *(const float4*)(Ap + off); a1 = *(const float4*)(Ap + off + 4);
            b0 = *(const float4*)(Bp + off); b1 = *(const float4*)(Bp + off + 4);
        }
        const short8 bfrag = *(const short8*)&Blds[wv * 16 + frow][fk];
#pragma unroll
        for (int f = 0; f < 4; ++f) {
            const short8 afrag = *(const short8*)&Alds[f * 16 + frow][fk];
            acc[f] = __builtin_amdgcn_mfma_f32_16x16x32_bf16(afrag, bfrag, acc[f], 0, 0, 0);
        }
    }

    const int col = bn * 64 + wv * 16 + frow;
    const float bias_v = bk[col];
    const int r0 = (lane >> 4) * 4;
#pragma unroll
    for (int f = 0; f < 4; ++f)
#pragma unroll
        for (int r = 0; r < 4; ++r)
            cp[(size_t)(bm * 64 + f * 16 + r0 + r) * DIM + col] = acc[f][r] + bias_v;
}

// ---------------- Kernel 2: out[b,n,s] = (1/512) * dot(cp[b,s,:], z[b,n,s,:]) ----
// LOOPED-BATCH variant — the R17 reps-diagnostic structure with real
// addresses. Measured: marginal pass cost 71 us (vs 94 one-shot) -> read
// stream sustains ~7.2 TB/s and the one-shot carries ~23 us ramp/tail.
// Each wave loops 4 groups of {8 nt z loads (batch) -> 4 dot/reduce/store},
// pointer-bumped; sched_barrier(0) between groups pins the measured batch
// cadence and caps VGPRs (~60 -> full occupancy). cp loaded once per wave.
#define NS ((size_t)128 * 512)         // n-stride in z (floats)
#define LD4(p)   (*(const f32x4*)(p))
#define LD4NT(p) (__builtin_nontemporal_load((const f32x4*)(p)))

__global__ __launch_bounds__(256) void dot_kernel(
    const float* __restrict__ z, const float* __restrict__ cp,
    float* __restrict__ out) {
    const int blk  = blockIdx.x;             // 0..4095
    const int bs   = blk >> 1;               // b*128 + s (0..2047)
    const int nh   = blk & 1;                // n-half (64 n's)
    const int wave = threadIdx.x >> 6;       // 0..3
    const int lane = threadIdx.x & 63;
    const int b = bs >> 7;
    const int s = bs & 127;

    // cp row -> registers (temporal; loaded once, reused for 16 n's)
    const float* cpr = cp + (size_t)bs * DIM + lane * 4;
    const f32x4 c0 = LD4(cpr);
    const f32x4 c1 = LD4(cpr + 256);

    // group g, slot i: n = nh*64 + g*16 + wave*4 + i
    const int nbase0 = nh * 64 + wave * 4;
    const float* zp = z + (((size_t)(b * 128 + nbase0)) * 128 + s) * DIM + lane * 4;
    float* outp = out + ((size_t)(b * 128 + nbase0)) * 128 + s;

#pragma unroll
    for (int g = 0; g < 4; ++g) {
        const f32x4 zA0 = LD4NT(zp + 0 * NS), zA1 = LD4NT(zp + 0 * NS + 256);
        const f32x4 zB0 = LD4NT(zp + 1 * NS), zB1 = LD4NT(zp + 1 * NS + 256);
        const f32x4 zC0 = LD4NT(zp + 2 * NS), zC1 = LD4NT(zp + 2 * NS + 256);
        const f32x4 zD0 = LD4NT(zp + 3 * NS), zD1 = LD4NT(zp + 3 * NS + 256);

#define SLOT(Z0, Z1, II)                                                      \
    {                                                                          \
        float acc = Z0[0] * c0[0];                                             \
        acc = fmaf(Z0[1], c0[1], acc);                                         \
        acc = fmaf(Z0[2], c0[2], acc);                                         \
        acc = fmaf(Z0[3], c0[3], acc);                                         \
        acc = fmaf(Z1[0], c1[0], acc);                                         \
        acc = fmaf(Z1[1], c1[1], acc);                                         \
        acc = fmaf(Z1[2], c1[2], acc);                                         \
        acc = fmaf(Z1[3], c1[3], acc);                                         \
        _Pragma("unroll")                                                      \
        for (int off = 32; off; off >>= 1) acc += __shfl_xor(acc, off);        \
        if (lane == 0) outp[(size_t)(II) * 128] = acc * (1.0f / 512.0f);       \
    }

        SLOT(zA0, zA1, 0)
        SLOT(zB0, zB1, 1)
        SLOT(zC0, zC1, 2)
        SLOT(zD0, zD1, 3)
#undef SLOT
        zp   += 16 * NS;                 // next group of 16 n's
        outp += 16 * 128;
        __builtin_amdgcn_sched_barrier(0);   // pin batch cadence (diag-measured)
    }
}

extern "C" void kernel_launch(void* const* d_in, const int* in_sizes, int n_in,
                              void* d_out, int out_size, void* d_ws, size_t ws_size,
                              hipStream_t stream) {
    const float* c    = (const float*)d_in[0];
    const float* z    = (const float*)d_in[1];
    const float* W    = (const float*)d_in[2];
    const float* bias = (const float*)d_in[3];
    const int*   kptr = (const int*)d_in[4];
    float* out = (float*)d_out;
    float* cp  = (float*)d_ws;   // 2048*512*4 = 4 MB scratch for c_proj

    // Kernel 1: 32 M-tiles x 8 N-tiles = 256 blocks, bf16 MFMA
    cproj_mfma<<<dim3(256), dim3(256), 0, stream>>>(c, W, bias, kptr, cp);
    // Kernel 2: 4096 blocks; each wave loops 4 batched groups (diag structure)
    dot_kernel<<<dim3(4096), dim3(256), 0, stream>>>(z, cp, out);
}